// Round 15
// baseline (145.424 us; speedup 1.0000x reference)
//
#include <hip/hip_runtime.h>

#define D_IN 256
#define D_OUT 128
#define ALPHA 0.2f
#define RB 64           // src nodes per bucket
#define RBSH 6
#define NBMAX 1600
#define CH 8192         // edges per bfill-role block
#define CAPG 1536       // fixed per-bucket key capacity (mean 1024, +16 sigma)
#define OVFCAP 32768

typedef __attribute__((ext_vector_type(8))) short bf16x8;
typedef __attribute__((ext_vector_type(4))) float f32x4;

__device__ inline unsigned short f2bf(float f) {
    unsigned int u = __float_as_uint(f);
    return (unsigned short)((u + 0x7FFFu + ((u >> 16) & 1u)) >> 16);
}
__device__ inline float bf2f(unsigned short u) {
    return __uint_as_float(((unsigned int)u) << 16);
}
// gfx950 native packed fp32->bf16 (RNE); no builtin exposed -> inline asm.
__device__ inline unsigned int cvt_pk_bf16(float lo, float hi) {
    unsigned int r;
    asm("v_cvt_pk_bf16_f32 %0, %1, %2" : "=v"(r) : "v"(lo), "v"(hi));
    return r;
}

// ---------------- W -> WTb (transposed bf16) ----------------
__global__ __launch_bounds__(256) void k_wt(const float* __restrict__ W,
                                            unsigned short* __restrict__ WTb) {
    const int ncol = blockIdx.x;
    const int k = threadIdx.x;
    WTb[(size_t)ncol * 256 + k] = f2bf(W[(size_t)k * 128 + ncol]);
}

// ===== fused heterogeneous kernel: blocks [0,nbf) = bfill, [nbf,..) = GEMM =====
// GEMM role: BARRIER-FREE. 4 waves/block, each wave owns 32 rows x 128 cols,
// stages its own 8KB LDS region; all hazards are wave-local (lgkmcnt ordered).
__global__ __launch_bounds__(256) void k_fused(const float* __restrict__ x,
                                               const unsigned short* __restrict__ WTb,
                                               const float* __restrict__ a,
                                               unsigned short* __restrict__ hb,
                                               float* __restrict__ f_src,
                                               float* __restrict__ f_dst, int n,
                                               const int* __restrict__ src,
                                               const int* __restrict__ dst,
                                               int* __restrict__ gcnt,
                                               int2* __restrict__ ovf,
                                               int* __restrict__ gkeys, int E, int nb,
                                               int nbf) {
    __shared__ char smem[32768];               // 32 KB union (bfill cnt/bas | 4x8KB wave tiles)
    const int t = threadIdx.x;

    if (blockIdx.x < nbf) {
        // ---------------- bfill role ----------------
        int* cnt = (int*)smem;                 // [NBMAX]
        int* bas = cnt + NBMAX;                // [NBMAX]
        const int e0 = blockIdx.x * CH;
        const int e1 = min(e0 + CH, E);
        for (int i = t; i < nb; i += 256) cnt[i] = 0;
        __syncthreads();
        for (int e = e0 + t; e < e1; e += 256) atomicAdd(&cnt[src[e] >> RBSH], 1);
        __syncthreads();
        for (int b = t; b < nb; b += 256) {
            int c = cnt[b];
            bas[b] = c ? atomicAdd(&gcnt[b], c) : 0;
            cnt[b] = 0;
        }
        __syncthreads();
        for (int e = e0 + t; e < e1; e += 256) {
            int s = src[e], d = dst[e];
            int b = s >> RBSH;
            int key = ((s & (RB - 1)) << 17) | d;
            int r = bas[b] + atomicAdd(&cnt[b], 1);
            if (r < CAPG) {
                gkeys[b * CAPG + r] = key;
            } else {
                int o = atomicAdd(&gcnt[nb], 1);
                if (o < OVFCAP) ovf[o] = make_int2(b, key);
            }
        }
        return;
    }

    // ---------------- GEMM role (wave-private, no __syncthreads) ----------------
    const int l = t & 63;
    const int w = t >> 6;                      // wave id 0..3
    const int lr = l & 15;
    const int g = l >> 4;                      // 0..3
    const int lk8 = g * 8;
    const int row0 = (blockIdx.x - nbf) * 128 + w * 32;   // wave's 32 rows
    unsigned short* sW = (unsigned short*)smem + w * 32 * 128;  // 8 KB private

    f32x4 acc[2][8] = {};
    const unsigned short* bp[8];
    #pragma unroll
    for (int ni = 0; ni < 8; ++ni)
        bp[ni] = WTb + (size_t)(ni * 16 + lr) * 256 + lk8;

    for (int half = 0; half < 2; ++half) {
        // ---- stage own 32 rows of this K-half: fp32 -> bf16 LDS (swizzled) ----
        #pragma unroll
        for (int it = 0; it < 8; ++it) {
            int r = it * 4 + g;
            int gr = row0 + r;
            float4 fa, fb;
            if (gr < n) {
                const float* xp = &x[(size_t)gr * D_IN + half * 128 + lr * 8];
                fa = *(const float4*)xp;
                fb = *(const float4*)(xp + 4);
            } else {
                fa = make_float4(0.f, 0.f, 0.f, 0.f);
                fb = fa;
            }
            uint4 v;
            v.x = cvt_pk_bf16(fa.x, fa.y);
            v.y = cvt_pk_bf16(fa.z, fa.w);
            v.z = cvt_pk_bf16(fb.x, fb.y);
            v.w = cvt_pk_bf16(fb.z, fb.w);
            int js = lr ^ ((r & 7) << 1);      // swizzled 16B granule
            *(uint4*)&sW[r * 128 + js * 8] = v;
        }
        // no barrier: same-wave ds_write -> ds_read ordering via lgkmcnt

        #pragma unroll
        for (int k0 = 0; k0 < 128; k0 += 32) {
            bf16x8 af[2], bfr[8];
            #pragma unroll
            for (int mi = 0; mi < 2; ++mi) {
                int row_l = mi * 16 + lr;
                int js = ((k0 >> 3) + g) ^ ((row_l & 7) << 1);
                af[mi] = *(const bf16x8*)&sW[row_l * 128 + js * 8];
            }
            #pragma unroll
            for (int ni = 0; ni < 8; ++ni)
                bfr[ni] = *(const bf16x8*)(bp[ni] + half * 128 + k0);
            #pragma unroll
            for (int mi = 0; mi < 2; ++mi)
                #pragma unroll
                for (int ni = 0; ni < 8; ++ni)
                    acc[mi][ni] = __builtin_amdgcn_mfma_f32_16x16x32_bf16(
                        af[mi], bfr[ni], acc[mi][ni], 0, 0, 0);
        }
        // no barrier: next half's ds_writes ordered after this half's ds_reads
    }

    // ---- hb store (C/D: col = ni*16 + lr, row = g*4 + q), cvt_pk pairs ----
    #pragma unroll
    for (int mi = 0; mi < 2; ++mi) {
        #pragma unroll
        for (int q = 0; q < 4; ++q) {
            int r = row0 + mi * 16 + g * 4 + q;
            if (r < n) {
                unsigned short* hp = &hb[(size_t)r * D_OUT + lr];
                #pragma unroll
                for (int np = 0; np < 4; ++np) {
                    unsigned int pk = cvt_pk_bf16(acc[mi][2 * np][q], acc[mi][2 * np + 1][q]);
                    hp[np * 32]      = (unsigned short)(pk & 0xFFFF);
                    hp[np * 32 + 16] = (unsigned short)(pk >> 16);
                }
            }
        }
    }

    // ---- fused f_src/f_dst: wave-local (lane holds cols ni*16+lr, ni=0..7) ----
    float asv[8], adv[8];
    #pragma unroll
    for (int ni = 0; ni < 8; ++ni) {
        asv[ni] = a[ni * 16 + lr];
        adv[ni] = a[D_OUT + ni * 16 + lr];
    }
    #pragma unroll
    for (int mi = 0; mi < 2; ++mi) {
        #pragma unroll
        for (int q = 0; q < 4; ++q) {
            float fs = 0.f, fd = 0.f;
            #pragma unroll
            for (int ni = 0; ni < 8; ++ni) {
                float v = acc[mi][ni][q];
                fs = fmaf(v, asv[ni], fs);
                fd = fmaf(v, adv[ni], fd);
            }
            #pragma unroll
            for (int m = 1; m < 16; m <<= 1) {
                fs += __shfl_xor(fs, m);
                fd += __shfl_xor(fd, m);
            }
            if (lr == 0) {
                int r = row0 + mi * 16 + g * 4 + q;
                if (r < n) {
                    f_src[r] = fs;
                    f_dst[r] = fd;
                }
            }
        }
    }
}

// -------- aggregation: block/bucket, LDS lists, 2-edge 32-lane pass 3 --------
__global__ __launch_bounds__(512, 8) void k_bagg(const unsigned short* __restrict__ hb,
                                                 const float* __restrict__ f_src,
                                                 const float* __restrict__ f_dst,
                                                 const int* __restrict__ gcnt,
                                                 const int2* __restrict__ ovf,
                                                 const int* __restrict__ gkeys,
                                                 float* __restrict__ out, int n, int nb) {
    __shared__ int2 sdw[CAPG];       // (dst, weight-bits), grouped by local src
    __shared__ int nbase[RB];
    __shared__ int ncnt[RB];
    __shared__ int ncur[RB];
    __shared__ float fsl[RB];
    __shared__ int sc[RB];
    const int t = threadIdx.x;
    const int b = blockIdx.x;
    const int s0 = b * RB;
    const int nn = min(RB, n - s0);
    const int beg = b * CAPG;
    const int stored = min(gcnt[b], CAPG);
    const int ovf_n = min(gcnt[nb], OVFCAP);

    for (int i = t; i < RB; i += 512) {
        ncnt[i] = 0;
        fsl[i] = (i < nn) ? f_src[s0 + i] : 0.f;
    }
    __syncthreads();

    for (int i = t; i < stored; i += 512)
        atomicAdd(&ncnt[gkeys[beg + i] >> 17], 1);
    __syncthreads();

    if (t < RB) sc[t] = ncnt[t];
    __syncthreads();
    for (int off = 1; off < RB; off <<= 1) {
        int v = 0;
        if (t < RB && t >= off) v = sc[t - off];
        __syncthreads();
        if (t < RB) sc[t] += v;
        __syncthreads();
    }
    if (t < RB) {
        nbase[t] = sc[t] - ncnt[t];
        ncur[t]  = sc[t] - ncnt[t];
    }
    __syncthreads();

    for (int i = t; i < stored; i += 512) {
        int k = gkeys[beg + i];
        int d = k & 0x1FFFF, ls = k >> 17;
        float tmp = fsl[ls] + f_dst[d];
        float w = __expf(-((tmp > 0.f) ? tmp : ALPHA * tmp));
        int pos = atomicAdd(&ncur[ls], 1);
        sdw[pos] = make_int2(d, __float_as_int(w));
    }
    __syncthreads();

    const int lane = t & 63, wid = t >> 6;
    const int cl = (lane & 31) * 4;
    const bool isB = lane >= 32;
    for (int ni = wid; ni < nn; ni += 8) {
        const int jb = nbase[ni];
        const int cn = ncnt[ni];
        const int halfA = (cn + 1) >> 1;
        const int halfB = cn - halfA;
        const int lim = isB ? halfB : halfA;
        const int jbh = jb + (isB ? halfA : 0);
        float a0 = 0.f, a1 = 0.f, a2 = 0.f, a3 = 0.f, rowsum = 0.f;
        #pragma unroll 4
        for (int it = 0; it < halfA; ++it) {
            bool valid = it < lim;
            int2 dw = sdw[valid ? (jbh + it) : jb];
            float w = valid ? __int_as_float(dw.y) : 0.f;
            ushort4 hv = *(const ushort4*)&hb[(size_t)dw.x * D_OUT + cl];
            rowsum += w;
            a0 = fmaf(w, bf2f(hv.x), a0);
            a1 = fmaf(w, bf2f(hv.y), a1);
            a2 = fmaf(w, bf2f(hv.z), a2);
            a3 = fmaf(w, bf2f(hv.w), a3);
        }
        if (ovf_n > 0) {
            for (int o = 0; o < ovf_n; ++o) {
                int2 ov = ovf[o];
                if (ov.x == b && (ov.y >> 17) == ni && !isB) {
                    int d = ov.y & 0x1FFFF;
                    float tmp = fsl[ni] + f_dst[d];
                    float w = __expf(-((tmp > 0.f) ? tmp : ALPHA * tmp));
                    ushort4 hv = *(const ushort4*)&hb[(size_t)d * D_OUT + cl];
                    rowsum += w;
                    a0 = fmaf(w, bf2f(hv.x), a0);
                    a1 = fmaf(w, bf2f(hv.y), a1);
                    a2 = fmaf(w, bf2f(hv.z), a2);
                    a3 = fmaf(w, bf2f(hv.w), a3);
                }
            }
        }
        rowsum += __shfl_xor(rowsum, 32);
        a0 += __shfl_xor(a0, 32);
        a1 += __shfl_xor(a1, 32);
        a2 += __shfl_xor(a2, 32);
        a3 += __shfl_xor(a3, 32);
        if (!isB) {
            float inv = 1.f / rowsum;
            a0 *= inv; a1 *= inv; a2 *= inv; a3 *= inv;
            a0 = (a0 > 0.f) ? a0 : (__expf(a0) - 1.f);
            a1 = (a1 > 0.f) ? a1 : (__expf(a1) - 1.f);
            a2 = (a2 > 0.f) ? a2 : (__expf(a2) - 1.f);
            a3 = (a3 > 0.f) ? a3 : (__expf(a3) - 1.f);
            *(float4*)&out[(size_t)(s0 + ni) * D_OUT + cl] =
                make_float4(a0, a1, a2, a3);
        }
    }
}

extern "C" void kernel_launch(void* const* d_in, const int* in_sizes, int n_in,
                              void* d_out, int out_size, void* d_ws, size_t ws_size,
                              hipStream_t stream) {
    const float* x    = (const float*)d_in[0];
    const int*   edge = (const int*)d_in[1];   // JAX no-x64: int64 -> int32
    const float* W    = (const float*)d_in[2];
    const float* a    = (const float*)d_in[3];
    float* out = (float*)d_out;

    const int n = in_sizes[0] / D_IN;
    const int E = in_sizes[1] / 2;
    const int* src = edge;
    const int* dst = edge + E;
    const int nb = (n + RB - 1) / RB;

    char* p = (char*)d_ws;
    unsigned short* hb  = (unsigned short*)p; p += (size_t)n * D_OUT * sizeof(unsigned short);
    unsigned short* WTb = (unsigned short*)p; p += (size_t)D_OUT * D_IN * sizeof(unsigned short);
    float* f_src = (float*)p;  p += (size_t)n * sizeof(float);
    float* f_dst = (float*)p;  p += (size_t)n * sizeof(float);
    int*  gcnt   = (int*)p;    p += (size_t)(nb + 1) * sizeof(int);
    int2* ovf    = (int2*)p;   p += (size_t)OVFCAP * sizeof(int2);
    int*  gkeys  = (int*)p;    p += (size_t)nb * CAPG * sizeof(int);

    const int gemm_blocks = (n + 127) / 128;
    const int nbf = (E + CH - 1) / CH;

    hipMemsetAsync(gcnt, 0, (size_t)(nb + 1) * sizeof(int), stream);
    k_wt<<<D_OUT, 256, 0, stream>>>(W, WTb);
    k_fused<<<nbf + gemm_blocks, 256, 0, stream>>>(x, WTb, a, hb, f_src, f_dst, n,
                                                   src, dst, gcnt, ovf, gkeys, E, nb, nbf);
    k_bagg<<<nb, 512, 0, stream>>>(hb, f_src, f_dst, gcnt, ovf, gkeys, out, n, nb);
}

// Round 16
// 133.466 us; speedup vs baseline: 1.0896x; 1.0896x over previous
//
#include <hip/hip_runtime.h>

#define D_IN 256
#define D_OUT 128
#define ALPHA 0.2f
#define RB 64           // src nodes per bucket
#define RBSH 6
#define NBMAX 1600
#define CH 8192         // edges per bfill-role block
#define CAPG 1536       // fixed per-bucket key capacity (mean 1024, +16 sigma)
#define OVFCAP 32768
#define LKH 128         // K-half staged in LDS (ushorts per row)
#define BM 64           // gemm-role rows per block

typedef __attribute__((ext_vector_type(8))) short bf16x8;
typedef __attribute__((ext_vector_type(4))) float f32x4;

__device__ inline unsigned short f2bf(float f) {
    unsigned int u = __float_as_uint(f);
    return (unsigned short)((u + 0x7FFFu + ((u >> 16) & 1u)) >> 16);
}
__device__ inline float bf2f(unsigned short u) {
    return __uint_as_float(((unsigned int)u) << 16);
}
// gfx950 native packed fp32->bf16 (RNE); no builtin exposed -> inline asm.
__device__ inline unsigned int cvt_pk_bf16(float lo, float hi) {
    unsigned int r;
    asm("v_cvt_pk_bf16_f32 %0, %1, %2" : "=v"(r) : "v"(lo), "v"(hi));
    return r;
}

// ---------------- W -> WTb (transposed bf16) ----------------
__global__ __launch_bounds__(256) void k_wt(const float* __restrict__ W,
                                            unsigned short* __restrict__ WTb) {
    const int ncol = blockIdx.x;
    const int k = threadIdx.x;
    WTb[(size_t)ncol * 256 + k] = f2bf(W[(size_t)k * 128 + ncol]);
}

// ===== fused heterogeneous kernel: blocks [0,nbf) = bfill, [nbf,..) = GEMM =====
// GEMM role: BM=64, K staged in 2 halves (16KB LDS), XOR-swizzled, 2x2 waves.
__global__ __launch_bounds__(256) void k_fused(const float* __restrict__ x,
                                               const unsigned short* __restrict__ WTb,
                                               const float* __restrict__ a,
                                               unsigned short* __restrict__ hb,
                                               float* __restrict__ f_src,
                                               float* __restrict__ f_dst, int n,
                                               const int* __restrict__ src,
                                               const int* __restrict__ dst,
                                               int* __restrict__ gcnt,
                                               int2* __restrict__ ovf,
                                               int* __restrict__ gkeys, int E, int nb,
                                               int nbf) {
    __shared__ char smem[BM * LKH * 2];        // 16 KB union (bfill cnt/bas | x tile)
    __shared__ float sFp[BM][2][2];            // gemm epilogue buffer, 1 KB
    const int t = threadIdx.x;

    if (blockIdx.x < nbf) {
        // ---------------- bfill role ----------------
        int* cnt = (int*)smem;                 // [NBMAX]
        int* bas = cnt + NBMAX;                // [NBMAX]  (2*1600*4 = 12.8KB < 16KB)
        const int e0 = blockIdx.x * CH;
        const int e1 = min(e0 + CH, E);
        for (int i = t; i < nb; i += 256) cnt[i] = 0;
        __syncthreads();
        for (int e = e0 + t; e < e1; e += 256) atomicAdd(&cnt[src[e] >> RBSH], 1);
        __syncthreads();
        for (int b = t; b < nb; b += 256) {
            int c = cnt[b];
            bas[b] = c ? atomicAdd(&gcnt[b], c) : 0;
            cnt[b] = 0;
        }
        __syncthreads();
        for (int e = e0 + t; e < e1; e += 256) {
            int s = src[e], d = dst[e];
            int b = s >> RBSH;
            int key = ((s & (RB - 1)) << 17) | d;
            int r = bas[b] + atomicAdd(&cnt[b], 1);
            if (r < CAPG) {
                gkeys[b * CAPG + r] = key;
            } else {
                int o = atomicAdd(&gcnt[nb], 1);
                if (o < OVFCAP) ovf[o] = make_int2(b, key);
            }
        }
        return;
    }

    // ---------------- GEMM role (BM=64, 2 K-halves, swizzled LDS) ----------------
    unsigned short* sA = (unsigned short*)smem;
    const int l = t & 63;
    const int w = t >> 6;
    const int wr = w >> 1, wc = w & 1;
    const int row0 = (blockIdx.x - nbf) * BM;
    const int col0 = wc * 64;
    const int lr = l & 15;
    const int g = l >> 4;
    const int lk8 = g * 8;

    f32x4 acc[2][4] = {};
    const unsigned short* bp[4];
    #pragma unroll
    for (int ni = 0; ni < 4; ++ni)
        bp[ni] = WTb + (size_t)(col0 + ni * 16 + lr) * 256 + lk8;

    #pragma unroll
    for (int half = 0; half < 2; ++half) {
        // ---- stage x[:, half*128 .. half*128+127] fp32 -> bf16 LDS ----
        {
            const int rr = t >> 4;          // 0..15
            const int cc = (t & 15) * 8;    // 0..120
            #pragma unroll
            for (int it = 0; it < 4; ++it) {
                int r = it * 16 + rr;
                int gr = row0 + r;
                float4 fa, fb;
                if (gr < n) {
                    const float* xp = &x[(size_t)gr * D_IN + half * LKH + cc];
                    fa = *(const float4*)xp;
                    fb = *(const float4*)(xp + 4);
                } else {
                    fa = make_float4(0.f, 0.f, 0.f, 0.f);
                    fb = fa;
                }
                uint4 v;
                v.x = cvt_pk_bf16(fa.x, fa.y);
                v.y = cvt_pk_bf16(fa.z, fa.w);
                v.z = cvt_pk_bf16(fb.x, fb.y);
                v.w = cvt_pk_bf16(fb.z, fb.w);
                int js = (cc >> 3) ^ ((r & 7) << 1);   // swizzled 16B block
                *(uint4*)&sA[r * LKH + js * 8] = v;
            }
        }
        __syncthreads();

        #pragma unroll
        for (int k0 = 0; k0 < LKH; k0 += 32) {
            bf16x8 af[2], bfr[4];
            #pragma unroll
            for (int mi = 0; mi < 2; ++mi) {
                int row_l = wr * 32 + mi * 16 + lr;
                int js = ((k0 >> 3) + g) ^ ((row_l & 7) << 1);
                af[mi] = *(const bf16x8*)&sA[row_l * LKH + js * 8];
            }
            #pragma unroll
            for (int ni = 0; ni < 4; ++ni)
                bfr[ni] = *(const bf16x8*)(bp[ni] + half * LKH + k0);
            #pragma unroll
            for (int mi = 0; mi < 2; ++mi)
                #pragma unroll
                for (int ni = 0; ni < 4; ++ni)
                    acc[mi][ni] = __builtin_amdgcn_mfma_f32_16x16x32_bf16(
                        af[mi], bfr[ni], acc[mi][ni], 0, 0, 0);
        }
        __syncthreads();
    }

    // ---- hb store (C/D: col = lane&15, row = g*4 + q), cvt_pk pairs ----
    #pragma unroll
    for (int mi = 0; mi < 2; ++mi) {
        #pragma unroll
        for (int q = 0; q < 4; ++q) {
            int r = row0 + wr * 32 + mi * 16 + g * 4 + q;
            if (r < n) {
                unsigned int a01 = cvt_pk_bf16(acc[mi][0][q], acc[mi][1][q]);
                unsigned int a23 = cvt_pk_bf16(acc[mi][2][q], acc[mi][3][q]);
                unsigned short* hp = &hb[(size_t)r * D_OUT + col0 + lr];
                hp[0]  = (unsigned short)(a01 & 0xFFFF);
                hp[16] = (unsigned short)(a01 >> 16);
                hp[32] = (unsigned short)(a23 & 0xFFFF);
                hp[48] = (unsigned short)(a23 >> 16);
            }
        }
    }

    // ---- fused f_src/f_dst from fp32 acc ----
    float asv[4], adv[4];
    #pragma unroll
    for (int ni = 0; ni < 4; ++ni) {
        asv[ni] = a[col0 + ni * 16 + lr];
        adv[ni] = a[D_OUT + col0 + ni * 16 + lr];
    }
    #pragma unroll
    for (int mi = 0; mi < 2; ++mi) {
        #pragma unroll
        for (int q = 0; q < 4; ++q) {
            float fs = 0.f, fd = 0.f;
            #pragma unroll
            for (int ni = 0; ni < 4; ++ni) {
                float v = acc[mi][ni][q];
                fs = fmaf(v, asv[ni], fs);
                fd = fmaf(v, adv[ni], fd);
            }
            #pragma unroll
            for (int m = 1; m < 16; m <<= 1) {
                fs += __shfl_xor(fs, m);
                fd += __shfl_xor(fd, m);
            }
            if (lr == 0) {
                int rl = wr * 32 + mi * 16 + g * 4 + q;
                sFp[rl][wc][0] = fs;
                sFp[rl][wc][1] = fd;
            }
        }
    }
    __syncthreads();
    if (t < BM) {
        int r = row0 + t;
        if (r < n) {
            f_src[r] = sFp[t][0][0] + sFp[t][1][0];
            f_dst[r] = sFp[t][0][1] + sFp[t][1][1];
        }
    }
}

// -------- aggregation: block/bucket, LDS lists, 2-edge 32-lane pass 3 --------
__global__ __launch_bounds__(512, 8) void k_bagg(const unsigned short* __restrict__ hb,
                                                 const float* __restrict__ f_src,
                                                 const float* __restrict__ f_dst,
                                                 const int* __restrict__ gcnt,
                                                 const int2* __restrict__ ovf,
                                                 const int* __restrict__ gkeys,
                                                 float* __restrict__ out, int n, int nb) {
    __shared__ int2 sdw[CAPG];       // (dst, weight-bits), grouped by local src
    __shared__ int nbase[RB];
    __shared__ int ncnt[RB];
    __shared__ int ncur[RB];
    __shared__ float fsl[RB];
    __shared__ int sc[RB];
    const int t = threadIdx.x;
    const int b = blockIdx.x;
    const int s0 = b * RB;
    const int nn = min(RB, n - s0);
    const int beg = b * CAPG;
    const int stored = min(gcnt[b], CAPG);
    const int ovf_n = min(gcnt[nb], OVFCAP);

    for (int i = t; i < RB; i += 512) {
        ncnt[i] = 0;
        fsl[i] = (i < nn) ? f_src[s0 + i] : 0.f;
    }
    __syncthreads();

    for (int i = t; i < stored; i += 512)
        atomicAdd(&ncnt[gkeys[beg + i] >> 17], 1);
    __syncthreads();

    if (t < RB) sc[t] = ncnt[t];
    __syncthreads();
    for (int off = 1; off < RB; off <<= 1) {
        int v = 0;
        if (t < RB && t >= off) v = sc[t - off];
        __syncthreads();
        if (t < RB) sc[t] += v;
        __syncthreads();
    }
    if (t < RB) {
        nbase[t] = sc[t] - ncnt[t];
        ncur[t]  = sc[t] - ncnt[t];
    }
    __syncthreads();

    for (int i = t; i < stored; i += 512) {
        int k = gkeys[beg + i];
        int d = k & 0x1FFFF, ls = k >> 17;
        float tmp = fsl[ls] + f_dst[d];
        float w = __expf(-((tmp > 0.f) ? tmp : ALPHA * tmp));
        int pos = atomicAdd(&ncur[ls], 1);
        sdw[pos] = make_int2(d, __float_as_int(w));
    }
    __syncthreads();

    const int lane = t & 63, wid = t >> 6;
    const int cl = (lane & 31) * 4;
    const bool isB = lane >= 32;
    for (int ni = wid; ni < nn; ni += 8) {
        const int jb = nbase[ni];
        const int cn = ncnt[ni];
        const int halfA = (cn + 1) >> 1;
        const int halfB = cn - halfA;
        const int lim = isB ? halfB : halfA;
        const int jbh = jb + (isB ? halfA : 0);
        float a0 = 0.f, a1 = 0.f, a2 = 0.f, a3 = 0.f, rowsum = 0.f;
        #pragma unroll 4
        for (int it = 0; it < halfA; ++it) {
            bool valid = it < lim;
            int2 dw = sdw[valid ? (jbh + it) : jb];
            float w = valid ? __int_as_float(dw.y) : 0.f;
            ushort4 hv = *(const ushort4*)&hb[(size_t)dw.x * D_OUT + cl];
            rowsum += w;
            a0 = fmaf(w, bf2f(hv.x), a0);
            a1 = fmaf(w, bf2f(hv.y), a1);
            a2 = fmaf(w, bf2f(hv.z), a2);
            a3 = fmaf(w, bf2f(hv.w), a3);
        }
        if (ovf_n > 0) {
            for (int o = 0; o < ovf_n; ++o) {
                int2 ov = ovf[o];
                if (ov.x == b && (ov.y >> 17) == ni && !isB) {
                    int d = ov.y & 0x1FFFF;
                    float tmp = fsl[ni] + f_dst[d];
                    float w = __expf(-((tmp > 0.f) ? tmp : ALPHA * tmp));
                    ushort4 hv = *(const ushort4*)&hb[(size_t)d * D_OUT + cl];
                    rowsum += w;
                    a0 = fmaf(w, bf2f(hv.x), a0);
                    a1 = fmaf(w, bf2f(hv.y), a1);
                    a2 = fmaf(w, bf2f(hv.z), a2);
                    a3 = fmaf(w, bf2f(hv.w), a3);
                }
            }
        }
        rowsum += __shfl_xor(rowsum, 32);
        a0 += __shfl_xor(a0, 32);
        a1 += __shfl_xor(a1, 32);
        a2 += __shfl_xor(a2, 32);
        a3 += __shfl_xor(a3, 32);
        if (!isB) {
            float inv = 1.f / rowsum;
            a0 *= inv; a1 *= inv; a2 *= inv; a3 *= inv;
            a0 = (a0 > 0.f) ? a0 : (__expf(a0) - 1.f);
            a1 = (a1 > 0.f) ? a1 : (__expf(a1) - 1.f);
            a2 = (a2 > 0.f) ? a2 : (__expf(a2) - 1.f);
            a3 = (a3 > 0.f) ? a3 : (__expf(a3) - 1.f);
            *(float4*)&out[(size_t)(s0 + ni) * D_OUT + cl] =
                make_float4(a0, a1, a2, a3);
        }
    }
}

extern "C" void kernel_launch(void* const* d_in, const int* in_sizes, int n_in,
                              void* d_out, int out_size, void* d_ws, size_t ws_size,
                              hipStream_t stream) {
    const float* x    = (const float*)d_in[0];
    const int*   edge = (const int*)d_in[1];   // JAX no-x64: int64 -> int32
    const float* W    = (const float*)d_in[2];
    const float* a    = (const float*)d_in[3];
    float* out = (float*)d_out;

    const int n = in_sizes[0] / D_IN;
    const int E = in_sizes[1] / 2;
    const int* src = edge;
    const int* dst = edge + E;
    const int nb = (n + RB - 1) / RB;

    char* p = (char*)d_ws;
    unsigned short* hb  = (unsigned short*)p; p += (size_t)n * D_OUT * sizeof(unsigned short);
    unsigned short* WTb = (unsigned short*)p; p += (size_t)D_OUT * D_IN * sizeof(unsigned short);
    float* f_src = (float*)p;  p += (size_t)n * sizeof(float);
    float* f_dst = (float*)p;  p += (size_t)n * sizeof(float);
    int*  gcnt   = (int*)p;    p += (size_t)(nb + 1) * sizeof(int);
    int2* ovf    = (int2*)p;   p += (size_t)OVFCAP * sizeof(int2);
    int*  gkeys  = (int*)p;    p += (size_t)nb * CAPG * sizeof(int);

    const int gemm_blocks = (n + BM - 1) / BM;
    const int nbf = (E + CH - 1) / CH;

    hipMemsetAsync(gcnt, 0, (size_t)(nb + 1) * sizeof(int), stream);
    k_wt<<<D_OUT, 256, 0, stream>>>(W, WTb);
    k_fused<<<nbf + gemm_blocks, 256, 0, stream>>>(x, WTb, a, hb, f_src, f_dst, n,
                                                   src, dst, gcnt, ovf, gkeys, E, nb, nbf);
    k_bagg<<<nb, 512, 0, stream>>>(hb, f_src, f_dst, gcnt, ovf, gkeys, out, n, nb);
}